// Round 1
// baseline (1561.250 us; speedup 1.0000x reference)
//
#include <hip/hip_runtime.h>
#include <math.h>

#define TPB 256
#define GT 128   // GEMM tile (rows and cols)
#define GK 16    // GEMM k-chunk

// ---------------------------------------------------------------------------
// Kernel 1: h = relu(f*w1)*w2 ; emb = h / max(||h||_2, 1e-12). One block/row.
// ---------------------------------------------------------------------------
__global__ __launch_bounds__(256) void normalize_kernel(
    const float* __restrict__ F, const float* __restrict__ w1,
    const float* __restrict__ w2, float* __restrict__ E, int D) {
  int row = blockIdx.x;
  int tid = threadIdx.x;
  __shared__ float red[TPB];
  size_t base = (size_t)row * D;
  float f = F[base + tid];
  float h = fmaxf(f * w1[tid], 0.0f) * w2[tid];
  red[tid] = h * h;
  __syncthreads();
  for (int o = TPB / 2; o > 0; o >>= 1) {
    if (tid < o) red[tid] += red[tid + o];
    __syncthreads();
  }
  float norm = fmaxf(sqrtf(red[0]), 1e-12f);
  E[base + tid] = h / norm;
}

// ---------------------------------------------------------------------------
// Kernel 2: C = E * E^T, fp32 vector-ALU GEMM.
// 128x128 tile per 256-thread block, 8x8 micro-tile per thread (2x2 quadrants
// of 4 so loads/stores are contiguous float4), K staged through LDS in
// chunks of 16.
// ---------------------------------------------------------------------------
__global__ __launch_bounds__(256) void gemm_nt_kernel(
    const float* __restrict__ E, float* __restrict__ C, int N, int D) {
  __shared__ float As[GK][GT];
  __shared__ float Bs[GK][GT];
  int tid = threadIdx.x;
  int tx = tid & 15;        // 0..15 -> columns
  int ty = tid >> 4;        // 0..15 -> rows
  int rowBase = blockIdx.y * GT;
  int colBase = blockIdx.x * GT;

  float acc[8][8];
#pragma unroll
  for (int i = 0; i < 8; ++i)
#pragma unroll
    for (int j = 0; j < 8; ++j) acc[i][j] = 0.0f;

  // staging assignment: thread loads 2 float4 for A and 2 for B per chunk
  int r0 = tid >> 2;              // 0..63
  int k40 = (tid & 3) << 2;       // 0,4,8,12
  const float* Ap0 = E + (size_t)(rowBase + r0) * D + k40;
  const float* Ap1 = E + (size_t)(rowBase + r0 + 64) * D + k40;
  const float* Bp0 = E + (size_t)(colBase + r0) * D + k40;
  const float* Bp1 = E + (size_t)(colBase + r0 + 64) * D + k40;

  for (int kc = 0; kc < D; kc += GK) {
    float4 a0 = *(const float4*)(Ap0 + kc);
    float4 a1 = *(const float4*)(Ap1 + kc);
    float4 b0 = *(const float4*)(Bp0 + kc);
    float4 b1 = *(const float4*)(Bp1 + kc);
    As[k40 + 0][r0] = a0.x; As[k40 + 1][r0] = a0.y;
    As[k40 + 2][r0] = a0.z; As[k40 + 3][r0] = a0.w;
    As[k40 + 0][r0 + 64] = a1.x; As[k40 + 1][r0 + 64] = a1.y;
    As[k40 + 2][r0 + 64] = a1.z; As[k40 + 3][r0 + 64] = a1.w;
    Bs[k40 + 0][r0] = b0.x; Bs[k40 + 1][r0] = b0.y;
    Bs[k40 + 2][r0] = b0.z; Bs[k40 + 3][r0] = b0.w;
    Bs[k40 + 0][r0 + 64] = b1.x; Bs[k40 + 1][r0 + 64] = b1.y;
    Bs[k40 + 2][r0 + 64] = b1.z; Bs[k40 + 3][r0 + 64] = b1.w;
    __syncthreads();

#pragma unroll
    for (int k = 0; k < GK; ++k) {
      float4 av0 = *(const float4*)&As[k][ty * 4];
      float4 av1 = *(const float4*)&As[k][64 + ty * 4];
      float4 bv0 = *(const float4*)&Bs[k][tx * 4];
      float4 bv1 = *(const float4*)&Bs[k][64 + tx * 4];
      float av[8] = {av0.x, av0.y, av0.z, av0.w, av1.x, av1.y, av1.z, av1.w};
      float bv[8] = {bv0.x, bv0.y, bv0.z, bv0.w, bv1.x, bv1.y, bv1.z, bv1.w};
#pragma unroll
      for (int ii = 0; ii < 8; ++ii)
#pragma unroll
        for (int jj = 0; jj < 8; ++jj)
          acc[ii][jj] = fmaf(av[ii], bv[jj], acc[ii][jj]);
    }
    __syncthreads();
  }

#pragma unroll
  for (int ii = 0; ii < 8; ++ii) {
    int r = rowBase + ((ii < 4) ? (ty * 4 + ii) : (64 + ty * 4 + (ii - 4)));
    float4 v0 = make_float4(acc[ii][0], acc[ii][1], acc[ii][2], acc[ii][3]);
    float4 v1 = make_float4(acc[ii][4], acc[ii][5], acc[ii][6], acc[ii][7]);
    *(float4*)&C[(size_t)r * N + colBase + tx * 4] = v0;
    *(float4*)&C[(size_t)r * N + colBase + 64 + tx * 4] = v1;
  }
}

// ---------------------------------------------------------------------------
// Kernel 3: per-row top-(k+1) mask + relu, in place on C. One block per row.
// Exact selection via 4-pass radix select (8-bit digits) on the monotone
// uint32 mapping of fp32; ties kept lowest-index-first (matches lax.top_k).
// ---------------------------------------------------------------------------
__global__ __launch_bounds__(256) void topk_kernel(
    float* __restrict__ C, const int* __restrict__ kptr, int N) {
  extern __shared__ unsigned int su[];       // N mapped values
  __shared__ unsigned int hist[256];
  __shared__ unsigned int sc[256];
  __shared__ unsigned int red[TPB];
  __shared__ unsigned int s_want, s_prefix, s_e;

  int tid = threadIdx.x;
  int EPT = N / TPB;                          // 40
  float* Crow = C + (size_t)blockIdx.x * N;

  // load + monotone map (order-preserving fp32 -> uint32)
  for (int i = 0; i < EPT; ++i) {
    int j = i * TPB + tid;
    unsigned int s = __float_as_uint(Crow[j]);
    su[j] = (s & 0x80000000u) ? ~s : (s | 0x80000000u);
  }
  unsigned int want0 = (unsigned int)(kptr[0] + 1);   // k+1 = 31
  if (tid == 0) { s_want = want0; s_prefix = 0u; }
  __syncthreads();

  unsigned int maskHi = 0u;
  for (int d = 3; d >= 0; --d) {
    int shift = d * 8;
    unsigned int prefix = s_prefix;   // written before previous barrier
    hist[tid] = 0u;
    __syncthreads();
    for (int i = 0; i < EPT; ++i) {
      unsigned int u = su[i * TPB + tid];
      if ((u & maskHi) == prefix)
        atomicAdd(&hist[(u >> shift) & 255u], 1u);
    }
    __syncthreads();
    // inclusive suffix scan over 256 bins (Hillis-Steele)
    sc[tid] = hist[tid];
    __syncthreads();
    for (int off = 1; off < 256; off <<= 1) {
      unsigned int add = (tid + off < 256) ? sc[tid + off] : 0u;
      __syncthreads();
      sc[tid] += add;
      __syncthreads();
    }
    unsigned int want_c = s_want;
    __syncthreads();                  // everyone reads want before selector writes
    unsigned int above = (tid < 255) ? sc[tid + 1] : 0u;
    if (sc[tid] >= want_c && above < want_c) {   // exactly one bin satisfies
      s_want = want_c - above;        // how many still needed inside this bin
      s_e = hist[tid];                // elements in this bin at this digit
      s_prefix = prefix | ((unsigned int)tid << shift);
    }
    __syncthreads();
    maskHi |= (0xFFu << shift);
  }

  unsigned int Tu = s_prefix;   // exact bit pattern of the 31st largest
  unsigned int need = s_want;   // # of ==Tu entries to keep (lowest index first)
  unsigned int e = s_e;         // total # of ==Tu entries
  int Jcut = N;                 // default: keep all equals (need == e)
  if (need < e) {
    // rare: duplicates at the boundary — binary search smallest index cutoff
    int lo = 0, hi = N - 1;
    while (lo < hi) {
      int mid = (lo + hi) >> 1;
      unsigned int cnt = 0u;
      for (int i = 0; i < EPT; ++i) {
        int j = i * TPB + tid;
        cnt += (j <= mid && su[j] == Tu) ? 1u : 0u;
      }
      red[tid] = cnt;
      __syncthreads();
      for (int o = TPB / 2; o > 0; o >>= 1) {
        if (tid < o) red[tid] += red[tid + o];
        __syncthreads();
      }
      unsigned int total = red[0];
      __syncthreads();
      if (total >= need) hi = mid; else lo = mid + 1;
    }
    Jcut = lo;
  }

  // masked relu rewrite, in place
  for (int i = 0; i < EPT; ++i) {
    int j = i * TPB + tid;
    unsigned int u = su[j];
    bool keep = (u > Tu) || (u == Tu && j <= Jcut);
    float v = __uint_as_float((u & 0x80000000u) ? (u ^ 0x80000000u) : ~u);
    Crow[j] = (keep && v > 0.0f) ? v : 0.0f;
  }
}

// ---------------------------------------------------------------------------
extern "C" void kernel_launch(void* const* d_in, const int* in_sizes, int n_in,
                              void* d_out, int out_size, void* d_ws, size_t ws_size,
                              hipStream_t stream) {
  const float* F  = (const float*)d_in[0];
  const float* w1 = (const float*)d_in[1];
  const float* w2 = (const float*)d_in[2];
  const int*   kp = (const int*)d_in[3];
  float* C = (float*)d_out;
  float* E = (float*)d_ws;          // 10240*256*4 = 10 MB scratch

  int D = in_sizes[1];              // 256
  int N = in_sizes[0] / D;          // 10240

  normalize_kernel<<<N, D, 0, stream>>>(F, w1, w2, E, D);

  dim3 grid(N / GT, N / GT);        // 80 x 80
  gemm_nt_kernel<<<grid, 256, 0, stream>>>(E, C, N, D);

  topk_kernel<<<N, TPB, N * sizeof(unsigned int), stream>>>(C, kp, N);
}

// Round 2
// 1253.842 us; speedup vs baseline: 1.2452x; 1.2452x over previous
//
#include <hip/hip_runtime.h>
#include <math.h>

#define TPB 256
#define GT 128   // GEMM tile (rows and cols)
#define GK 16    // GEMM k-chunk
#define CAP 1536 // top-k candidate buffer capacity

// ---------------------------------------------------------------------------
// Kernel 1: h = relu(f*w1)*w2 ; emb = h / max(||h||_2, 1e-12). One block/row.
// ---------------------------------------------------------------------------
__global__ __launch_bounds__(256) void normalize_kernel(
    const float* __restrict__ F, const float* __restrict__ w1,
    const float* __restrict__ w2, float* __restrict__ E, int D) {
  int row = blockIdx.x;
  int tid = threadIdx.x;
  __shared__ float red[TPB];
  size_t base = (size_t)row * D;
  float f = F[base + tid];
  float h = fmaxf(f * w1[tid], 0.0f) * w2[tid];
  red[tid] = h * h;
  __syncthreads();
  for (int o = TPB / 2; o > 0; o >>= 1) {
    if (tid < o) red[tid] += red[tid + o];
    __syncthreads();
  }
  float norm = fmaxf(sqrtf(red[0]), 1e-12f);
  E[base + tid] = h / norm;
}

// ---------------------------------------------------------------------------
// Kernel 2: C = E * E^T, fp32 vector-ALU GEMM. (unchanged from R1)
// ---------------------------------------------------------------------------
__global__ __launch_bounds__(256) void gemm_nt_kernel(
    const float* __restrict__ E, float* __restrict__ C, int N, int D) {
  __shared__ float As[GK][GT];
  __shared__ float Bs[GK][GT];
  int tid = threadIdx.x;
  int tx = tid & 15;
  int ty = tid >> 4;
  int rowBase = blockIdx.y * GT;
  int colBase = blockIdx.x * GT;

  float acc[8][8];
#pragma unroll
  for (int i = 0; i < 8; ++i)
#pragma unroll
    for (int j = 0; j < 8; ++j) acc[i][j] = 0.0f;

  int r0 = tid >> 2;
  int k40 = (tid & 3) << 2;
  const float* Ap0 = E + (size_t)(rowBase + r0) * D + k40;
  const float* Ap1 = E + (size_t)(rowBase + r0 + 64) * D + k40;
  const float* Bp0 = E + (size_t)(colBase + r0) * D + k40;
  const float* Bp1 = E + (size_t)(colBase + r0 + 64) * D + k40;

  for (int kc = 0; kc < D; kc += GK) {
    float4 a0 = *(const float4*)(Ap0 + kc);
    float4 a1 = *(const float4*)(Ap1 + kc);
    float4 b0 = *(const float4*)(Bp0 + kc);
    float4 b1 = *(const float4*)(Bp1 + kc);
    As[k40 + 0][r0] = a0.x; As[k40 + 1][r0] = a0.y;
    As[k40 + 2][r0] = a0.z; As[k40 + 3][r0] = a0.w;
    As[k40 + 0][r0 + 64] = a1.x; As[k40 + 1][r0 + 64] = a1.y;
    As[k40 + 2][r0 + 64] = a1.z; As[k40 + 3][r0 + 64] = a1.w;
    Bs[k40 + 0][r0] = b0.x; Bs[k40 + 1][r0] = b0.y;
    Bs[k40 + 2][r0] = b0.z; Bs[k40 + 3][r0] = b0.w;
    Bs[k40 + 0][r0 + 64] = b1.x; Bs[k40 + 1][r0 + 64] = b1.y;
    Bs[k40 + 2][r0 + 64] = b1.z; Bs[k40 + 3][r0 + 64] = b1.w;
    __syncthreads();

#pragma unroll
    for (int k = 0; k < GK; ++k) {
      float4 av0 = *(const float4*)&As[k][ty * 4];
      float4 av1 = *(const float4*)&As[k][64 + ty * 4];
      float4 bv0 = *(const float4*)&Bs[k][tx * 4];
      float4 bv1 = *(const float4*)&Bs[k][64 + tx * 4];
      float av[8] = {av0.x, av0.y, av0.z, av0.w, av1.x, av1.y, av1.z, av1.w};
      float bv[8] = {bv0.x, bv0.y, bv0.z, bv0.w, bv1.x, bv1.y, bv1.z, bv1.w};
#pragma unroll
      for (int ii = 0; ii < 8; ++ii)
#pragma unroll
        for (int jj = 0; jj < 8; ++jj)
          acc[ii][jj] = fmaf(av[ii], bv[jj], acc[ii][jj]);
    }
    __syncthreads();
  }

#pragma unroll
  for (int ii = 0; ii < 8; ++ii) {
    int r = rowBase + ((ii < 4) ? (ty * 4 + ii) : (64 + ty * 4 + (ii - 4)));
    float4 v0 = make_float4(acc[ii][0], acc[ii][1], acc[ii][2], acc[ii][3]);
    float4 v1 = make_float4(acc[ii][4], acc[ii][5], acc[ii][6], acc[ii][7]);
    *(float4*)&C[(size_t)r * N + colBase + tx * 4] = v0;
    *(float4*)&C[(size_t)r * N + colBase + 64 + tx * 4] = v1;
  }
}

// ---------------------------------------------------------------------------
// Kernel 3 (rewritten): per-row top-(k+1) mask + relu, in place on C.
// Candidate-pruning exact select: row lives in registers (40 u32/thread);
// L31 = want-th largest of per-thread maxima (provable lower bound on the
// want-th largest element); gather candidates >= L31 (expected ~want);
// exact rank among candidates with lowest-index tie-break (lax.top_k order).
// All LDS reads are wave-broadcast (same address) -> no bank conflicts.
// ---------------------------------------------------------------------------
__global__ __launch_bounds__(256) void topk_kernel(
    float* __restrict__ C, const int* __restrict__ kptr, int N) {
  __shared__ unsigned int lm[TPB];       // per-thread local maxima / reduce buf
  __shared__ unsigned int cu[CAP];       // candidate mapped values
  __shared__ int ci[CAP];                // candidate original indices
  __shared__ unsigned int s_cnt;
  __shared__ unsigned int s_L31, s_Tu;
  __shared__ int s_Jcut;

  int tid = threadIdx.x;
  int EPT = N / TPB;                     // 40 elements/thread
  int NV4 = EPT / 4;                     // 10 float4 loads/thread
  float* Crow = C + (size_t)blockIdx.x * N;
  unsigned int want = (unsigned int)(kptr[0] + 1);   // k+1

  // ---- pass 1: load row (float4, coalesced), map to order-preserving uint,
  //      keep in registers, track local max
  unsigned int u[40];
  unsigned int lmax = 0u;
  for (int i = 0; i < NV4; ++i) {
    float4 v = *(const float4*)&Crow[(i * TPB + tid) * 4];
    float fv[4] = {v.x, v.y, v.z, v.w};
#pragma unroll
    for (int c = 0; c < 4; ++c) {
      unsigned int s = __float_as_uint(fv[c]);
      unsigned int m = (s & 0x80000000u) ? ~s : (s | 0x80000000u);
      u[i * 4 + c] = m;
      lmax = (m > lmax) ? m : lmax;
    }
  }
  lm[tid] = lmax;
  if (tid == 0) s_cnt = 0u;
  __syncthreads();

  // ---- L31: want-th largest of the 256 local maxima (rank by full scan,
  //      broadcast LDS reads, index tie-break makes ranks a permutation)
  {
    unsigned int r = 0;
    for (int j = 0; j < TPB; ++j) {
      unsigned int vj = lm[j];
      r += (vj > lmax) || (vj == lmax && j < tid);
    }
    if (r == want - 1) s_L31 = lmax;
  }
  __syncthreads();
  unsigned int L31 = s_L31;

  // ---- gather candidates >= L31 (guaranteed >= want of them exist)
  for (int i = 0; i < EPT; ++i) {
    if (u[i] >= L31) {
      unsigned int pos = atomicAdd(&s_cnt, 1u);
      if (pos < CAP) { cu[pos] = u[i]; ci[pos] = i * 4 % 4; /* placeholder */ }
      // note: real index computed below; overwrite properly:
      if (pos < CAP) {
        int v4 = i / 4, c = i % 4;
        ci[pos] = (v4 * TPB + tid) * 4 + c;
      }
    }
  }
  __syncthreads();
  unsigned int c_total = s_cnt;

  if (c_total <= CAP) {
    // ---- exact rank among candidates; rank==want-1 defines Tu and Jcut
    for (unsigned int i = tid; i < c_total; i += TPB) {
      unsigned int ui = cu[i];
      int ii = ci[i];
      unsigned int r = 0;
      for (unsigned int j = 0; j < c_total; ++j) {
        unsigned int uj = cu[j];
        r += (uj > ui) || (uj == ui && ci[j] < ii);
      }
      if (r == want - 1) { s_Tu = ui; s_Jcut = ii; }
    }
    __syncthreads();
  } else {
    // ---- rare degenerate fallback: bit-exact bisection on mapped value
    unsigned int lo = 0u, hi = 0xFFFFFFFFu;
    while (lo < hi) {
      unsigned int mid = lo + ((hi - lo) >> 1);
      unsigned int cnt = 0;
      for (int i = 0; i < EPT; ++i) cnt += (u[i] > mid) ? 1u : 0u;
      lm[tid] = cnt;
      __syncthreads();
      for (int o = TPB / 2; o > 0; o >>= 1) {
        if (tid < o) lm[tid] += lm[tid + o];
        __syncthreads();
      }
      unsigned int g = lm[0];
      __syncthreads();
      if (g < want) hi = mid; else lo = mid + 1u;
    }
    unsigned int Tu = lo;
    // count above, then bisect index cutoff among equals
    unsigned int cnt = 0;
    for (int i = 0; i < EPT; ++i) cnt += (u[i] > Tu) ? 1u : 0u;
    lm[tid] = cnt;
    __syncthreads();
    for (int o = TPB / 2; o > 0; o >>= 1) {
      if (tid < o) lm[tid] += lm[tid + o];
      __syncthreads();
    }
    unsigned int need = want - lm[0];
    __syncthreads();
    int jlo = 0, jhi = N - 1;
    while (jlo < jhi) {
      int jmid = (jlo + jhi) >> 1;
      unsigned int cc = 0;
      for (int i = 0; i < EPT; ++i) {
        int v4 = i / 4, cc2 = i % 4;
        int jj = (v4 * TPB + tid) * 4 + cc2;
        cc += (u[i] == Tu && jj <= jmid) ? 1u : 0u;
      }
      lm[tid] = cc;
      __syncthreads();
      for (int o = TPB / 2; o > 0; o >>= 1) {
        if (tid < o) lm[tid] += lm[tid + o];
        __syncthreads();
      }
      unsigned int tot = lm[0];
      __syncthreads();
      if (tot >= need) jhi = jmid; else jlo = jmid + 1;
    }
    if (tid == 0) { s_Tu = Tu; s_Jcut = jlo; }
    __syncthreads();
  }

  unsigned int Tu = s_Tu;
  int Jcut = s_Jcut;

  // ---- rewrite from registers: keep & relu, else zero (float4 stores)
  for (int i = 0; i < NV4; ++i) {
    float out[4];
#pragma unroll
    for (int c = 0; c < 4; ++c) {
      unsigned int m = u[i * 4 + c];
      int j = (i * TPB + tid) * 4 + c;
      bool keep = (m > Tu) || (m == Tu && j <= Jcut);
      float v = __uint_as_float((m & 0x80000000u) ? (m ^ 0x80000000u) : ~m);
      out[c] = (keep && v > 0.0f) ? v : 0.0f;
    }
    *(float4*)&Crow[(i * TPB + tid) * 4] = make_float4(out[0], out[1], out[2], out[3]);
  }
}

// ---------------------------------------------------------------------------
extern "C" void kernel_launch(void* const* d_in, const int* in_sizes, int n_in,
                              void* d_out, int out_size, void* d_ws, size_t ws_size,
                              hipStream_t stream) {
  const float* F  = (const float*)d_in[0];
  const float* w1 = (const float*)d_in[1];
  const float* w2 = (const float*)d_in[2];
  const int*   kp = (const int*)d_in[3];
  float* C = (float*)d_out;
  float* E = (float*)d_ws;          // 10240*256*4 = 10 MB scratch

  int D = in_sizes[1];              // 256
  int N = in_sizes[0] / D;          // 10240

  normalize_kernel<<<N, D, 0, stream>>>(F, w1, w2, E, D);

  dim3 grid(N / GT, N / GT);        // 80 x 80
  gemm_nt_kernel<<<grid, 256, 0, stream>>>(E, C, N, D);

  topk_kernel<<<N, TPB, 0, stream>>>(C, kp, N);
}

// Round 3
// 666.833 us; speedup vs baseline: 2.3413x; 1.8803x over previous
//
#include <hip/hip_runtime.h>
#include <math.h>

#define N_NODES 10240
#define DIM 256
#define TPB 256
#define CAP 1536

typedef _Float16 half8 __attribute__((ext_vector_type(8)));
typedef float f32x4 __attribute__((ext_vector_type(4)));

__device__ __forceinline__ void async_load16(const void* g, void* l) {
  __builtin_amdgcn_global_load_lds(
      (const __attribute__((address_space(1))) unsigned int*)g,
      (__attribute__((address_space(3))) unsigned int*)l, 16, 0, 0);
}

// ---------------------------------------------------------------------------
// Kernel 1: h = relu(f*w1)*w2 ; e = h/max(||h||,1e-12); split e into fp16
// hi (P0) and scaled lo (P1 = fp16((e-P0)*2^11)). One block per row.
// ---------------------------------------------------------------------------
__global__ __launch_bounds__(256) void norm_split_kernel(
    const float* __restrict__ F, const float* __restrict__ w1,
    const float* __restrict__ w2, _Float16* __restrict__ P0,
    _Float16* __restrict__ P1) {
  int row = blockIdx.x, tid = threadIdx.x;
  __shared__ float red[TPB];
  size_t base = (size_t)row * DIM + tid;
  float h = fmaxf(F[base] * w1[tid], 0.0f) * w2[tid];
  red[tid] = h * h;
  __syncthreads();
  for (int o = TPB / 2; o > 0; o >>= 1) {
    if (tid < o) red[tid] += red[tid + o];
    __syncthreads();
  }
  float e = h / fmaxf(sqrtf(red[0]), 1e-12f);
  _Float16 p0 = (_Float16)e;
  _Float16 p1 = (_Float16)((e - (float)p0) * 2048.0f);
  P0[base] = p0;
  P1[base] = p1;
}

// ---------------------------------------------------------------------------
// Kernel 2: C = E*E^T via fp16x3 MFMA (m97-style structure).
// 128x128 tile / 256 threads (4 waves, each 64x64), BK=64, 3 K-passes:
//   acc  = P0*P1s^T + P1s*P0^T        (cross terms, scaled by 2^11)
//   acc *= 2^-11
//   acc += P0*P0^T                    (main term)
// LDS tiles stored as XOR-swizzled 16B units: unit(m,g) = m*8 + (g^(m&7)),
// which keeps global_load_lds's lane-contiguous constraint AND makes the
// ds_read_b128 fragment reads ~conflict-free.
// ---------------------------------------------------------------------------
__global__ __launch_bounds__(256) void gemm_mfma_kernel(
    const _Float16* __restrict__ P0, const _Float16* __restrict__ P1,
    float* __restrict__ C) {
  __shared__ char smem[32768];
  char* AsB = smem;            // 128 rows x 64 halves (16 KB), swizzled
  char* BsB = smem + 16384;

  int tid = threadIdx.x;
  int lane = tid & 63;
  int w = tid >> 6;
  int wr = (w >> 1) * 64;      // wave's row quadrant in the 128-tile
  int wc = (w & 1) * 64;       // wave's col quadrant
  int quad = lane >> 4;
  int mr = lane & 15;
  int rowBase = blockIdx.y * 128;
  int colBase = blockIdx.x * 128;

  // staging assignments: 4 16B units per thread per tile (1024 units total)
  size_t rowOffA[4], rowOffB[4];
  int ldsOff[4];
#pragma unroll
  for (int i = 0; i < 4; ++i) {
    int u = tid + i * 256;
    int m = u >> 3;
    int g = (u & 7) ^ (m & 7);
    ldsOff[i] = u * 16;
    rowOffA[i] = (size_t)(rowBase + m) * DIM + g * 8;
    rowOffB[i] = (size_t)(colBase + m) * DIM + g * 8;
  }

  // fragment ds_read byte offsets: [kstep s][tile t]
  int fOffA[2][4], fOffB[2][4];
#pragma unroll
  for (int s = 0; s < 2; ++s)
#pragma unroll
    for (int t = 0; t < 4; ++t) {
      int g = s * 4 + quad;
      int mA = wr + t * 16 + mr;
      fOffA[s][t] = (mA * 8 + (g ^ (mA & 7))) * 16;
      int mB = wc + t * 16 + mr;
      fOffB[s][t] = (mB * 8 + (g ^ (mB & 7))) * 16;
    }

  f32x4 acc[4][4];
#pragma unroll
  for (int t = 0; t < 4; ++t)
#pragma unroll
    for (int u2 = 0; u2 < 4; ++u2) acc[t][u2] = (f32x4)0.0f;

  const _Float16* Aseg[3] = {P0, P1, P0};
  const _Float16* Bseg[3] = {P1, P0, P0};

  for (int pass = 0; pass < 3; ++pass) {
    if (pass == 2) {
      const float sc = 1.0f / 2048.0f;
#pragma unroll
      for (int t = 0; t < 4; ++t)
#pragma unroll
        for (int u2 = 0; u2 < 4; ++u2)
#pragma unroll
          for (int r = 0; r < 4; ++r) acc[t][u2][r] *= sc;
    }
    const _Float16* Ap = Aseg[pass];
    const _Float16* Bp = Bseg[pass];
    for (int c = 0; c < 4; ++c) {
      int kb = c * 64;
#pragma unroll
      for (int i = 0; i < 4; ++i)
        async_load16(Ap + rowOffA[i] + kb, AsB + ldsOff[i]);
#pragma unroll
      for (int i = 0; i < 4; ++i)
        async_load16(Bp + rowOffB[i] + kb, BsB + ldsOff[i]);
      __syncthreads();   // drains vmcnt -> LDS tiles valid
#pragma unroll
      for (int s = 0; s < 2; ++s) {
        half8 af[4], bf[4];
#pragma unroll
        for (int t = 0; t < 4; ++t) {
          af[t] = *(const half8*)(AsB + fOffA[s][t]);
          bf[t] = *(const half8*)(BsB + fOffB[s][t]);
        }
#pragma unroll
        for (int t = 0; t < 4; ++t)
#pragma unroll
          for (int u2 = 0; u2 < 4; ++u2)
            acc[t][u2] = __builtin_amdgcn_mfma_f32_16x16x32_f16(
                af[t], bf[u2], acc[t][u2], 0, 0, 0);
      }
      __syncthreads();   // all waves done reading before next stage
    }
  }

  // epilogue: C/D layout col=lane&15, row=quad*4+reg
#pragma unroll
  for (int t = 0; t < 4; ++t) {
    int gr = rowBase + wr + t * 16 + quad * 4;
#pragma unroll
    for (int u2 = 0; u2 < 4; ++u2) {
      int gc = colBase + wc + u2 * 16 + mr;
      float* cp = C + (size_t)gr * N_NODES + gc;
      cp[0] = acc[t][u2][0];
      cp[(size_t)N_NODES] = acc[t][u2][1];
      cp[(size_t)2 * N_NODES] = acc[t][u2][2];
      cp[(size_t)3 * N_NODES] = acc[t][u2][3];
    }
  }
}

// ---------------------------------------------------------------------------
// Kernel 3: per-row top-(k+1) mask + relu, in place. Compile-time N so the
// 40-element per-thread row slice fully unrolls into VGPRs (R2 version had
// runtime bounds -> dynamic indexing -> scratch spills, ~2x extra traffic).
// ---------------------------------------------------------------------------
__global__ __launch_bounds__(256) void topk_kernel(
    float* __restrict__ C, const int* __restrict__ kptr) {
  constexpr int EPT = N_NODES / TPB;   // 40
  constexpr int NV4 = EPT / 4;         // 10
  __shared__ unsigned int lm[TPB];
  __shared__ unsigned int cu[CAP];
  __shared__ int ci[CAP];
  __shared__ unsigned int s_cnt, s_L31, s_Tu;
  __shared__ int s_Jcut;

  int tid = threadIdx.x;
  float* Crow = C + (size_t)blockIdx.x * N_NODES;
  unsigned int want = (unsigned int)(kptr[0] + 1);   // k+1

  // load row slice into registers; order-preserving uint map; local max
  unsigned int u[EPT];
  unsigned int lmax = 0u;
#pragma unroll
  for (int i = 0; i < NV4; ++i) {
    float4 v = *(const float4*)&Crow[(i * TPB + tid) * 4];
    float fv[4] = {v.x, v.y, v.z, v.w};
#pragma unroll
    for (int c = 0; c < 4; ++c) {
      unsigned int s = __float_as_uint(fv[c]);
      unsigned int m = (s & 0x80000000u) ? ~s : (s | 0x80000000u);
      u[i * 4 + c] = m;
      lmax = (m > lmax) ? m : lmax;
    }
  }
  lm[tid] = lmax;
  if (tid == 0) s_cnt = 0u;
  __syncthreads();

  // L31 = want-th largest of the 256 local maxima (broadcast LDS scan)
  {
    unsigned int r = 0;
    for (int j = 0; j < TPB; ++j) {
      unsigned int vj = lm[j];
      r += (vj > lmax) || (vj == lmax && j < tid);
    }
    if (r == want - 1) s_L31 = lmax;
  }
  __syncthreads();
  unsigned int L31 = s_L31;

  // gather candidates >= L31 (guaranteed >= want exist)
#pragma unroll
  for (int i = 0; i < EPT; ++i) {
    if (u[i] >= L31) {
      unsigned int pos = atomicAdd(&s_cnt, 1u);
      if (pos < CAP) {
        cu[pos] = u[i];
        ci[pos] = ((i / 4) * TPB + tid) * 4 + (i % 4);
      }
    }
  }
  __syncthreads();
  unsigned int c_total = s_cnt;

  if (c_total <= CAP) {
    // exact rank among candidates; rank==want-1 -> threshold + index cutoff
    for (unsigned int i = tid; i < c_total; i += TPB) {
      unsigned int ui = cu[i];
      int ii = ci[i];
      unsigned int r = 0;
      for (unsigned int j = 0; j < c_total; ++j) {
        unsigned int uj = cu[j];
        r += (uj > ui) || (uj == ui && ci[j] < ii);
      }
      if (r == want - 1) { s_Tu = ui; s_Jcut = ii; }
    }
    __syncthreads();
  } else {
    // degenerate fallback: bit-exact bisection on mapped value
    unsigned int lo = 0u, hi = 0xFFFFFFFFu;
    while (lo < hi) {
      unsigned int mid = lo + ((hi - lo) >> 1);
      unsigned int cnt = 0;
#pragma unroll
      for (int i = 0; i < EPT; ++i) cnt += (u[i] > mid) ? 1u : 0u;
      lm[tid] = cnt;
      __syncthreads();
      for (int o = TPB / 2; o > 0; o >>= 1) {
        if (tid < o) lm[tid] += lm[tid + o];
        __syncthreads();
      }
      unsigned int gcnt = lm[0];
      __syncthreads();
      if (gcnt < want) hi = mid; else lo = mid + 1u;
    }
    unsigned int Tu = lo;
    unsigned int cnt = 0;
#pragma unroll
    for (int i = 0; i < EPT; ++i) cnt += (u[i] > Tu) ? 1u : 0u;
    lm[tid] = cnt;
    __syncthreads();
    for (int o = TPB / 2; o > 0; o >>= 1) {
      if (tid < o) lm[tid] += lm[tid + o];
      __syncthreads();
    }
    unsigned int need = want - lm[0];
    __syncthreads();
    int jlo = 0, jhi = N_NODES - 1;
    while (jlo < jhi) {
      int jmid = (jlo + jhi) >> 1;
      unsigned int cc = 0;
#pragma unroll
      for (int i = 0; i < EPT; ++i) {
        int jj = ((i / 4) * TPB + tid) * 4 + (i % 4);
        cc += (u[i] == Tu && jj <= jmid) ? 1u : 0u;
      }
      lm[tid] = cc;
      __syncthreads();
      for (int o = TPB / 2; o > 0; o >>= 1) {
        if (tid < o) lm[tid] += lm[tid + o];
        __syncthreads();
      }
      unsigned int tot = lm[0];
      __syncthreads();
      if (tot >= need) jhi = jmid; else jlo = jmid + 1;
    }
    if (tid == 0) { s_Tu = Tu; s_Jcut = jlo; }
    __syncthreads();
  }

  unsigned int Tu = s_Tu;
  int Jcut = s_Jcut;

  // rewrite from registers: keep & relu, else zero
#pragma unroll
  for (int i = 0; i < NV4; ++i) {
    float out[4];
#pragma unroll
    for (int c = 0; c < 4; ++c) {
      unsigned int m = u[i * 4 + c];
      int j = (i * TPB + tid) * 4 + c;
      bool keep = (m > Tu) || (m == Tu && j <= Jcut);
      float v = __uint_as_float((m & 0x80000000u) ? (m ^ 0x80000000u) : ~m);
      out[c] = (keep && v > 0.0f) ? v : 0.0f;
    }
    *(float4*)&Crow[(i * TPB + tid) * 4] =
        make_float4(out[0], out[1], out[2], out[3]);
  }
}

// ---------------------------------------------------------------------------
extern "C" void kernel_launch(void* const* d_in, const int* in_sizes, int n_in,
                              void* d_out, int out_size, void* d_ws, size_t ws_size,
                              hipStream_t stream) {
  const float* F  = (const float*)d_in[0];
  const float* w1 = (const float*)d_in[1];
  const float* w2 = (const float*)d_in[2];
  const int*   kp = (const int*)d_in[3];
  float* C = (float*)d_out;
  _Float16* P0 = (_Float16*)d_ws;                    // N*D fp16 = 5.24 MB
  _Float16* P1 = P0 + (size_t)N_NODES * DIM;         // N*D fp16 = 5.24 MB

  norm_split_kernel<<<N_NODES, DIM, 0, stream>>>(F, w1, w2, P0, P1);

  dim3 grid(N_NODES / 128, N_NODES / 128);           // 80 x 80
  gemm_mfma_kernel<<<grid, 256, 0, stream>>>(P0, P1, C);

  topk_kernel<<<N_NODES, TPB, 0, stream>>>(C, kp);
}